// Round 7
// baseline (48.566 us; speedup 1.0000x reference)
//
#include <hip/hip_runtime.h>
#include <hip/hip_bf16.h>

#define N_ROWS 8192
#define DIM 128

typedef short v8s __attribute__((ext_vector_type(8)));   // 8 bf16 (4 VGPRs) MFMA A/B frag
typedef float v4f __attribute__((ext_vector_type(4)));   // MFMA C/D frag
typedef unsigned int u32;

constexpr int NS = 16;                // j-splits (blockIdx.y): 1024 blocks = 4/CU
constexpr int CW = N_ROWS / NS;       // 512 j-rows per split
constexpr int NSLOT = NS;             // partial slots (one per j-split)
constexpr int TILE_J = 32;            // LDS-staged j-rows per tile
constexpr int NT = CW / TILE_J;       // 16 tiles per block
constexpr int TB = TILE_J * DIM * 2;  // 8 KB per buffer
constexpr float THRESH = 0.25f;       // sqrt(sqrt(d^2)) + 1e-8 < 0.5  <=>  |d| < 0.25
constexpr float C1 = 14.426950408889634f;  // 10*log2(e): exp(10*dot-10) = 2^(C1*dot - C1)

// global->LDS async copy; size must be a literal (macro keeps it one).
#define GLDS(gptr, lptr, sz)                                                   \
  __builtin_amdgcn_global_load_lds(                                            \
      (const __attribute__((address_space(1))) u32*)(gptr),                    \
      (__attribute__((address_space(3))) u32*)(lptr), sz, 0, 0)

__device__ __forceinline__ unsigned short f2bf(float f) {
  __hip_bfloat16 h = __float2bfloat16(f);
  return __builtin_bit_cast(unsigned short, h);
}

// ---------------- kernel 1: L2-normalize rows, cast to bf16 ----------------
__global__ __launch_bounds__(256) void knorm(const float* __restrict__ emb,
                                             unsigned short* __restrict__ ebf) {
  const int row  = blockIdx.x * 4 + (threadIdx.x >> 6);  // one wave per row
  const int lane = threadIdx.x & 63;
  const float2 v = *reinterpret_cast<const float2*>(emb + (size_t)row * DIM + lane * 2);
  float ss = fmaf(v.x, v.x, v.y * v.y);
#pragma unroll
  for (int off = 32; off > 0; off >>= 1) ss += __shfl_xor(ss, off);
  const float rn = 1.0f / sqrtf(ss);
  const unsigned int packed =
      (unsigned int)f2bf(v.x * rn) | ((unsigned int)f2bf(v.y * rn) << 16);
  *reinterpret_cast<unsigned int*>(ebf + (size_t)row * DIM + lane * 2) = packed;
}

// ---------------- kernel 2: fused sim-GEMM + row stats ----------------
// R6 structure (LDS-staged A, persistent B-frags, swizzled reads) + T3/T4:
// 3 LDS buffers, prefetch depth 2, counted s_waitcnt vmcnt(2) + raw s_barrier
// per tile instead of __syncthreads' full vmcnt(0) drain. Buffer safety:
// stage(t+2) targets buf (t-1)%3, whose ds_reads completed before this
// iteration's barrier (MFMA consumption forces read completion in iter t-1).
__global__ __launch_bounds__(256) void kmain(const unsigned short* __restrict__ ebf,
                                             const float* __restrict__ props,
                                             float* __restrict__ part) {
  const int lane = threadIdx.x & 63;
  const int w    = threadIdx.x >> 6;
  const int l15  = lane & 15;
  const int g    = lane >> 4;          // 0..3
  const int i0   = blockIdx.x * 128;   // block i-range
  const int iw0  = i0 + w * 32;        // wave i-range (32 cols)
  const int jbase = blockIdx.y * CW;
  const int kb   = g * 8;              // k element offset within a 32-k step

  __shared__ __align__(1024) char sA[3 * TB + CW * 4];
  char* sprops = sA + 3 * TB;

  const int icol0 = iw0 + l15;         // n=0 column for this lane
  const int icol1 = iw0 + 16 + l15;    // n=1 column

  // persistent B-frags: lane holds e[icol][kb..kb+8)
  v8s bfr0[4], bfr1[4];
#pragma unroll
  for (int k = 0; k < 4; ++k) {
    bfr0[k] = *reinterpret_cast<const v8s*>(ebf + (size_t)icol0 * DIM + k * 32 + kb);
    bfr1[k] = *reinterpret_cast<const v8s*>(ebf + (size_t)icol1 * DIM + k * 32 + kb);
  }
  const float pc0 = props[icol0];
  const float pc1 = props[icol1];

  // stage one 32-row A-tile: 2 GLDS/thread; LDS linear, source pre-swizzled
  auto stageA = [&](char* base, int tile) {
    const int jrow0 = jbase + tile * TILE_J;
#pragma unroll
    for (int q = 0; q < 2; ++q) {
      const int row  = q * 16 + w * 4 + g;               // LDS row this lane-group fills
      const int colb = (l15 << 4) ^ ((row & 7) << 4);    // pre-swizzled source byte-col
      GLDS(ebf + (size_t)(jrow0 + row) * DIM + (colb >> 1),
           base + q * 4096 + w * 1024, 16);
    }
  };

  // prologue: props first (oldest), then tiles 0 and 1 -> 6 GLDS outstanding
#pragma unroll
  for (int r = 0; r < 2; ++r)
    GLDS(props + jbase + r * 256 + w * 64 + lane, sprops + r * 1024 + w * 256, 4);
  stageA(sA + 0 * TB, 0);
  stageA(sA + 1 * TB, 1);

  // split accumulators (r-parity) to halve serial fp-add chain depth
  float es0a = 0.f, es0b = 0.f, es1a = 0.f, es1b = 0.f;
  float ms0a = 0.f, ms0b = 0.f, ms1a = 0.f, ms1b = 0.f;
  float ct0a = 0.f, ct0b = 0.f, ct1a = 0.f, ct1b = 0.f;

  const int swz = (l15 & 7) << 4;

  for (int t = 0; t < NT; ++t) {
    // tile t ready when only the (≤1) newer stage's 2 GLDS may be outstanding
    if (t < NT - 1) {
      asm volatile("s_waitcnt vmcnt(2)" ::: "memory");
    } else {
      asm volatile("s_waitcnt vmcnt(0)" ::: "memory");
    }
    __builtin_amdgcn_s_barrier();

    if (t + 2 < NT) stageA(sA + ((t + 2) % 3) * TB, t + 2);  // into buf (t-1)%3

    char* base = sA + (t % 3) * TB;
#pragma unroll
    for (int s = 0; s < 2; ++s) {
      const int jrow0 = jbase + t * TILE_J + s * 16;
      const int row   = s * 16 + l15;
      v8s af[4];
#pragma unroll
      for (int k = 0; k < 4; ++k)
        af[k] = *reinterpret_cast<const v8s*>(base + row * 256 + ((k * 64 + g * 16) ^ swz));
      const float4 pj = *reinterpret_cast<const float4*>(sprops + (t * 128 + s * 64 + g * 16));

      v4f acc0 = {0.f, 0.f, 0.f, 0.f}, acc1 = {0.f, 0.f, 0.f, 0.f};
#pragma unroll
      for (int k = 0; k < 4; ++k) {
        acc0 = __builtin_amdgcn_mfma_f32_16x16x32_bf16(af[k], bfr0[k], acc0, 0, 0, 0);
        acc1 = __builtin_amdgcn_mfma_f32_16x16x32_bf16(af[k], bfr1[k], acc1, 0, 0, 0);
      }

      const float pjv[4] = {pj.x, pj.y, pj.z, pj.w};
      if ((unsigned)(jrow0 - i0) < 128u) {   // subtile may contain the diagonal
#pragma unroll
        for (int r = 0; r < 4; ++r) {
          const int jr = jrow0 + g * 4 + r;
          float& es0 = (r & 2) ? es0b : es0a;  float& es1 = (r & 2) ? es1b : es1a;
          float& ms0 = (r & 2) ? ms0b : ms0a;  float& ms1 = (r & 2) ? ms1b : ms1a;
          float& ct0 = (r & 2) ? ct0b : ct0a;  float& ct1 = (r & 2) ? ct1b : ct1a;
          {
            const float dot = acc0[r];
            const bool  neq = (jr != icol0);
            const float ex  = __builtin_amdgcn_exp2f(fmaf(dot, C1, -C1));
            es0 += neq ? ex : 0.f;
            const float mskf = (neq && (fabsf(pc0 - pjv[r]) < THRESH)) ? 1.f : 0.f;
            ct0 += mskf;
            ms0 = fmaf(mskf, dot, ms0);
          }
          {
            const float dot = acc1[r];
            const bool  neq = (jr != icol1);
            const float ex  = __builtin_amdgcn_exp2f(fmaf(dot, C1, -C1));
            es1 += neq ? ex : 0.f;
            const float mskf = (neq && (fabsf(pc1 - pjv[r]) < THRESH)) ? 1.f : 0.f;
            ct1 += mskf;
            ms1 = fmaf(mskf, dot, ms1);
          }
        }
      } else {
#pragma unroll
        for (int r = 0; r < 4; ++r) {
          float& es0 = (r & 2) ? es0b : es0a;  float& es1 = (r & 2) ? es1b : es1a;
          float& ms0 = (r & 2) ? ms0b : ms0a;  float& ms1 = (r & 2) ? ms1b : ms1a;
          float& ct0 = (r & 2) ? ct0b : ct0a;  float& ct1 = (r & 2) ? ct1b : ct1a;
          {
            const float dot = acc0[r];
            es0 += __builtin_amdgcn_exp2f(fmaf(dot, C1, -C1));
            const float mskf = (fabsf(pc0 - pjv[r]) < THRESH) ? 1.f : 0.f;
            ct0 += mskf;
            ms0 = fmaf(mskf, dot, ms0);
          }
          {
            const float dot = acc1[r];
            es1 += __builtin_amdgcn_exp2f(fmaf(dot, C1, -C1));
            const float mskf = (fabsf(pc1 - pjv[r]) < THRESH) ? 1.f : 0.f;
            ct1 += mskf;
            ms1 = fmaf(mskf, dot, ms1);
          }
        }
      }
    }
  }

  float es0 = es0a + es0b, es1 = es1a + es1b;
  float ms0 = ms0a + ms0b, ms1 = ms1a + ms1b;
  float ct0 = ct0a + ct0b, ct1 = ct1a + ct1b;

  // sum the 4 g-groups (lanes ^16, ^32); then lanes g==0 hold full stats for their i
#pragma unroll
  for (int off = 16; off <= 32; off <<= 1) {
    es0 += __shfl_xor(es0, off);  es1 += __shfl_xor(es1, off);
    ms0 += __shfl_xor(ms0, off);  ms1 += __shfl_xor(ms1, off);
    ct0 += __shfl_xor(ct0, off);  ct1 += __shfl_xor(ct1, off);
  }

  if (g == 0) {
    float* p0 = part + (size_t)blockIdx.y * 3 * N_ROWS;   // slot = j-split; i disjoint per bx
    p0[icol0]              = es0;
    p0[N_ROWS + icol0]     = ms0;
    p0[2 * N_ROWS + icol0] = ct0;
    p0[icol1]              = es1;
    p0[N_ROWS + icol1]     = ms1;
    p0[2 * N_ROWS + icol1] = ct1;
  }
}

// ---------------- kernel 3: per-row finalize + per-block partial sums ----------------
__global__ __launch_bounds__(256) void kreduce(const float* __restrict__ part,
                                               float* __restrict__ bs,
                                               float* __restrict__ bc) {
  const int row = blockIdx.x * 256 + threadIdx.x;
  float es = 0.f, ms = 0.f, ct = 0.f;
#pragma unroll
  for (int sp = 0; sp < NSLOT; ++sp) {
    const float* p0 = part + (size_t)sp * 3 * N_ROWS;
    es += p0[row];
    ms += p0[N_ROWS + row];
    ct += p0[2 * N_ROWS + row];
  }
  const float lse = 10.0f + logf(es);                       // logsumexp, M=10
  const float per = (ct * lse - 10.0f * ms) / fmaxf(ct, 1.0f);
  float val = (ct > 0.f) ? per : 0.f;
  float vld = (ct > 0.f) ? 1.f : 0.f;
#pragma unroll
  for (int off = 32; off > 0; off >>= 1) {
    val += __shfl_xor(val, off);
    vld += __shfl_xor(vld, off);
  }
  __shared__ float sv[4], sc[4];
  const int wid = threadIdx.x >> 6;
  if ((threadIdx.x & 63) == 0) { sv[wid] = val; sc[wid] = vld; }
  __syncthreads();
  if (threadIdx.x == 0) {
    bs[blockIdx.x] = sv[0] + sv[1] + sv[2] + sv[3];
    bc[blockIdx.x] = sc[0] + sc[1] + sc[2] + sc[3];
  }
}

// ---------------- kernel 4: final scalar ----------------
__global__ __launch_bounds__(64) void kfin(const float* __restrict__ bs,
                                           const float* __restrict__ bc,
                                           float* __restrict__ out) {
  const int l = threadIdx.x;
  float s = (l < 32) ? bs[l] : 0.f;
  float c = (l < 32) ? bc[l] : 0.f;
#pragma unroll
  for (int off = 32; off > 0; off >>= 1) {
    s += __shfl_xor(s, off);
    c += __shfl_xor(c, off);
  }
  if (l == 0) out[0] = (c > 0.f) ? (s / c) : 0.f;
}

extern "C" void kernel_launch(void* const* d_in, const int* in_sizes, int n_in,
                              void* d_out, int out_size, void* d_ws, size_t ws_size,
                              hipStream_t stream) {
  const float* emb   = (const float*)d_in[0];
  const float* props = (const float*)d_in[1];
  float* out = (float*)d_out;

  // ws layout: [0, 2MB) bf16 normalized embeddings; then NSLOT*3*N f32 partials; then 64 f32
  unsigned short* ebf = (unsigned short*)d_ws;
  const size_t EBF_BYTES  = (size_t)N_ROWS * DIM * 2;
  const size_t PART_BYTES = (size_t)NSLOT * 3 * N_ROWS * 4;
  float* part = (float*)((char*)d_ws + EBF_BYTES);
  float* bs   = (float*)((char*)d_ws + EBF_BYTES + PART_BYTES);
  float* bc   = bs + 32;

  knorm<<<N_ROWS / 4, 256, 0, stream>>>(emb, ebf);
  kmain<<<dim3(N_ROWS / 128, NS), 256, 0, stream>>>(ebf, props, part);
  kreduce<<<N_ROWS / 256, 256, 0, stream>>>(part, bs, bc);
  kfin<<<1, 64, 0, stream>>>(bs, bc, out);
}

// Round 8
// 46.466 us; speedup vs baseline: 1.0452x; 1.0452x over previous
//
#include <hip/hip_runtime.h>
#include <hip/hip_bf16.h>

#define N_ROWS 8192
#define DIM 128

typedef short v8s  __attribute__((ext_vector_type(8)));   // 8 bf16 (4 VGPRs) MFMA A/B frag
typedef float v16f __attribute__((ext_vector_type(16)));  // 32x32 MFMA C/D frag
typedef unsigned int u32;

constexpr int NS = 16;                // j-splits (blockIdx.y): 1024 blocks = 4/CU
constexpr int CW = N_ROWS / NS;       // 512 j-rows per split
constexpr int NSLOT = NS;             // partial slots (one per j-split)
constexpr int TILE_J = 32;            // LDS-staged j-rows per tile (one 32x32 subtile)
constexpr int NT = CW / TILE_J;       // 16 tiles per block
constexpr int TB = TILE_J * DIM * 2;  // 8 KB per buffer
constexpr float THRESH = 0.25f;       // sqrt(sqrt(d^2)) + 1e-8 < 0.5  <=>  |d| < 0.25
constexpr float C1 = 14.426950408889634f;  // 10*log2(e): exp(10*dot-10) = 2^(C1*dot - C1)

// global->LDS async copy; size must be a literal (macro keeps it one).
#define GLDS(gptr, lptr, sz)                                                   \
  __builtin_amdgcn_global_load_lds(                                            \
      (const __attribute__((address_space(1))) u32*)(gptr),                    \
      (__attribute__((address_space(3))) u32*)(lptr), sz, 0, 0)

__device__ __forceinline__ unsigned short f2bf(float f) {
  __hip_bfloat16 h = __float2bfloat16(f);
  return __builtin_bit_cast(unsigned short, h);
}

// ---------------- kernel 1: L2-normalize rows, cast to bf16 ----------------
__global__ __launch_bounds__(256) void knorm(const float* __restrict__ emb,
                                             unsigned short* __restrict__ ebf) {
  const int row  = blockIdx.x * 4 + (threadIdx.x >> 6);  // one wave per row
  const int lane = threadIdx.x & 63;
  const float2 v = *reinterpret_cast<const float2*>(emb + (size_t)row * DIM + lane * 2);
  float ss = fmaf(v.x, v.x, v.y * v.y);
#pragma unroll
  for (int off = 32; off > 0; off >>= 1) ss += __shfl_xor(ss, off);
  const float rn = 1.0f / sqrtf(ss);
  const unsigned int packed =
      (unsigned int)f2bf(v.x * rn) | ((unsigned int)f2bf(v.y * rn) << 16);
  *reinterpret_cast<unsigned int*>(ebf + (size_t)row * DIM + lane * 2) = packed;
}

// ---------------- kernel 2: fused sim-GEMM + row stats, 32x32 MFMA ----------------
// R6 skeleton (2 LDS buffers, __syncthreads, global_load_lds, pre-swizzled
// source) but the wave tile is one v_mfma_f32_32x32x16_bf16 chain:
//  - A bytes/lane per 32 j-rows: 128 B (vs 256 B with 16x16x32) -> LDS port
//    traffic halved (the R6 binding pipe, ~10.3 us floor -> ~5.5).
//  - 8 ds_read_b128 + 8 MFMA per tile (vs 16+16).
//  - one i-col per lane (icol = iw0 + (lane&31)): stats = 6 regs, final
//    reduce = one shfl_xor(32).
// C/D layout (m74/m101): col = lane&31, row = (reg&3) + 8*(reg>>2) + 4*(lane>>5).
__global__ __launch_bounds__(256) void kmain(const unsigned short* __restrict__ ebf,
                                             const float* __restrict__ props,
                                             float* __restrict__ part) {
  const int lane = threadIdx.x & 63;
  const int w    = threadIdx.x >> 6;
  const int l15  = lane & 15;          // staging decomposition
  const int g4   = lane >> 4;          // 0..3 (staging)
  const int r31  = lane & 31;          // compute: A-row / C-col index
  const int hi   = lane >> 5;          // 0..1  (compute half)
  const int i0   = blockIdx.x * 128;   // block i-range
  const int iw0  = i0 + w * 32;        // wave i-range (32 cols)
  const int jbase = blockIdx.y * CW;

  __shared__ __align__(1024) char sA[2 * TB + CW * 4];
  char* sprops = sA + 2 * TB;

  const int icol = iw0 + r31;          // this lane's output column

  // persistent B-frags: frag kk holds e[icol][kk*16 + hi*8 .. +8)
  v8s bfr[8];
#pragma unroll
  for (int kk = 0; kk < 8; ++kk)
    bfr[kk] = *reinterpret_cast<const v8s*>(ebf + (size_t)icol * DIM + kk * 16 + hi * 8);
  const float pc = props[icol];

  // stage props[jbase .. +512) into LDS (2 rounds x 4B/thread)
#pragma unroll
  for (int r = 0; r < 2; ++r)
    GLDS(props + jbase + r * 256 + w * 64 + lane, sprops + r * 1024 + w * 256, 4);

  // stage one 32-row A-tile: 2 GLDS/thread; LDS linear, source pre-swizzled
  // (LDS slot s of row r holds global 16B-chunk s ^ (r&7))
  auto stageA = [&](char* base, int tile) {
    const int jrow0 = jbase + tile * TILE_J;
#pragma unroll
    for (int q = 0; q < 2; ++q) {
      const int row  = q * 16 + w * 4 + g4;              // LDS row this lane-group fills
      const int colb = (l15 << 4) ^ ((row & 7) << 4);    // pre-swizzled source byte-col
      GLDS(ebf + (size_t)(jrow0 + row) * DIM + (colb >> 1),
           base + q * 4096 + w * 1024, 16);
    }
  };

  stageA(sA, 0);
  __syncthreads();                     // tile0 + props ready (vmcnt(0) drain)

  float es2[2] = {0.f, 0.f}, ms2[2] = {0.f, 0.f}, ct2[2] = {0.f, 0.f};
  const int rswz = (r31 & 7) << 4;     // read-side XOR swizzle for this lane's row

  for (int t = 0; t < NT; ++t) {
    if (t + 1 < NT) stageA(sA + ((t + 1) & 1) * TB, t + 1);  // prefetch next tile

    char* base = sA + (t & 1) * TB;
    const int jrow0 = jbase + t * TILE_J;

    // A-frags: frag kk = e[jrow0 + r31][kk*16 + hi*8 .. +8) via swizzled slot
    v8s af[8];
#pragma unroll
    for (int kk = 0; kk < 8; ++kk)
      af[kk] = *reinterpret_cast<const v8s*>(
          base + r31 * 256 + ((kk * 32 + hi * 16) ^ rswz));

    // pj for this lane's 16 rows: rows (e + 8q + 4hi); broadcast LDS reads
    float pjf[16];
#pragma unroll
    for (int q = 0; q < 4; ++q) {
      const float4 v = *reinterpret_cast<const float4*>(
          sprops + t * 128 + hi * 16 + q * 32);
      pjf[q * 4 + 0] = v.x; pjf[q * 4 + 1] = v.y;
      pjf[q * 4 + 2] = v.z; pjf[q * 4 + 3] = v.w;
    }

    v16f acc = {0.f, 0.f, 0.f, 0.f, 0.f, 0.f, 0.f, 0.f,
                0.f, 0.f, 0.f, 0.f, 0.f, 0.f, 0.f, 0.f};
#pragma unroll
    for (int kk = 0; kk < 8; ++kk)
      acc = __builtin_amdgcn_mfma_f32_32x32x16_bf16(af[kk], bfr[kk], acc, 0, 0, 0);

    if ((unsigned)(jrow0 - i0) < 128u) {   // subtile may contain the diagonal
#pragma unroll
      for (int reg = 0; reg < 16; ++reg) {
        const int jr = jrow0 + (reg & 3) + 8 * (reg >> 2) + 4 * hi;
        const float dot = acc[reg];
        const bool  neq = (jr != icol);
        const float ex  = __builtin_amdgcn_exp2f(fmaf(dot, C1, -C1));
        es2[reg & 1] += neq ? ex : 0.f;
        const float mskf = (neq && (fabsf(pc - pjf[reg]) < THRESH)) ? 1.f : 0.f;
        ct2[reg & 1] += mskf;
        ms2[reg & 1] = fmaf(mskf, dot, ms2[reg & 1]);
      }
    } else {
#pragma unroll
      for (int reg = 0; reg < 16; ++reg) {
        const float dot = acc[reg];
        es2[reg & 1] += __builtin_amdgcn_exp2f(fmaf(dot, C1, -C1));
        const float mskf = (fabsf(pc - pjf[reg]) < THRESH) ? 1.f : 0.f;
        ct2[reg & 1] += mskf;
        ms2[reg & 1] = fmaf(mskf, dot, ms2[reg & 1]);
      }
    }
    __syncthreads();   // all reads of cur done; next tile staged
  }

  // combine split accumulators, then sum the two hi-halves (lanes l and l+32
  // hold complementary j-row subsets for the same icol)
  float es = es2[0] + es2[1];
  float ms = ms2[0] + ms2[1];
  float ct = ct2[0] + ct2[1];
  es += __shfl_xor(es, 32);
  ms += __shfl_xor(ms, 32);
  ct += __shfl_xor(ct, 32);

  if (hi == 0) {
    float* p0 = part + (size_t)blockIdx.y * 3 * N_ROWS;  // slot = j-split; i disjoint per bx
    p0[icol]              = es;
    p0[N_ROWS + icol]     = ms;
    p0[2 * N_ROWS + icol] = ct;
  }
}

// ---------------- kernel 3: per-row finalize + per-block partial sums ----------------
__global__ __launch_bounds__(256) void kreduce(const float* __restrict__ part,
                                               float* __restrict__ bs,
                                               float* __restrict__ bc) {
  const int row = blockIdx.x * 256 + threadIdx.x;
  float es = 0.f, ms = 0.f, ct = 0.f;
#pragma unroll
  for (int sp = 0; sp < NSLOT; ++sp) {
    const float* p0 = part + (size_t)sp * 3 * N_ROWS;
    es += p0[row];
    ms += p0[N_ROWS + row];
    ct += p0[2 * N_ROWS + row];
  }
  const float lse = 10.0f + logf(es);                       // logsumexp, M=10
  const float per = (ct * lse - 10.0f * ms) / fmaxf(ct, 1.0f);
  float val = (ct > 0.f) ? per : 0.f;
  float vld = (ct > 0.f) ? 1.f : 0.f;
#pragma unroll
  for (int off = 32; off > 0; off >>= 1) {
    val += __shfl_xor(val, off);
    vld += __shfl_xor(vld, off);
  }
  __shared__ float sv[4], sc[4];
  const int wid = threadIdx.x >> 6;
  if ((threadIdx.x & 63) == 0) { sv[wid] = val; sc[wid] = vld; }
  __syncthreads();
  if (threadIdx.x == 0) {
    bs[blockIdx.x] = sv[0] + sv[1] + sv[2] + sv[3];
    bc[blockIdx.x] = sc[0] + sc[1] + sc[2] + sc[3];
  }
}

// ---------------- kernel 4: final scalar ----------------
__global__ __launch_bounds__(64) void kfin(const float* __restrict__ bs,
                                           const float* __restrict__ bc,
                                           float* __restrict__ out) {
  const int l = threadIdx.x;
  float s = (l < 32) ? bs[l] : 0.f;
  float c = (l < 32) ? bc[l] : 0.f;
#pragma unroll
  for (int off = 32; off > 0; off >>= 1) {
    s += __shfl_xor(s, off);
    c += __shfl_xor(c, off);
  }
  if (l == 0) out[0] = (c > 0.f) ? (s / c) : 0.f;
}

extern "C" void kernel_launch(void* const* d_in, const int* in_sizes, int n_in,
                              void* d_out, int out_size, void* d_ws, size_t ws_size,
                              hipStream_t stream) {
  const float* emb   = (const float*)d_in[0];
  const float* props = (const float*)d_in[1];
  float* out = (float*)d_out;

  // ws layout: [0, 2MB) bf16 normalized embeddings; then NSLOT*3*N f32 partials; then 64 f32
  unsigned short* ebf = (unsigned short*)d_ws;
  const size_t EBF_BYTES  = (size_t)N_ROWS * DIM * 2;
  const size_t PART_BYTES = (size_t)NSLOT * 3 * N_ROWS * 4;
  float* part = (float*)((char*)d_ws + EBF_BYTES);
  float* bs   = (float*)((char*)d_ws + EBF_BYTES + PART_BYTES);
  float* bc   = bs + 32;

  knorm<<<N_ROWS / 4, 256, 0, stream>>>(emb, ebf);
  kmain<<<dim3(N_ROWS / 128, NS), 256, 0, stream>>>(ebf, props, part);
  kreduce<<<N_ROWS / 256, 256, 0, stream>>>(part, bs, bc);
  kfin<<<1, 64, 0, stream>>>(bs, bc, out);
}

// Round 9
// 45.598 us; speedup vs baseline: 1.0651x; 1.0191x over previous
//
#include <hip/hip_runtime.h>
#include <hip/hip_bf16.h>

#define N_ROWS 8192
#define DIM 128

typedef short v8s  __attribute__((ext_vector_type(8)));   // 8 bf16 (4 VGPRs) MFMA A/B frag
typedef float v16f __attribute__((ext_vector_type(16)));  // 32x32 MFMA C/D frag
typedef float v2f  __attribute__((ext_vector_type(2)));   // packed-f32 pair (v_pk_*)
typedef unsigned int u32;

constexpr int NS = 16;                // j-splits (blockIdx.y)
constexpr int CW = N_ROWS / NS;       // 512 j-rows per split
constexpr int NSLOT = NS;             // partial slots (one per j-split)
constexpr int TILE_J = 32;            // LDS-staged j-rows per tile
constexpr int NT = CW / TILE_J;       // 16 tiles per block
constexpr int TB = TILE_J * DIM * 2;  // 8 KB per buffer
constexpr int BI = 256;               // block i-width (8 waves x 32 cols)
constexpr float T2 = 0.0625f;         // THRESH^2: |pi-pj|<0.25 <=> d^2<0.0625
constexpr float C1 = 14.426950408889634f;  // 10*log2(e): exp(10*dot-10)=2^(C1*dot-C1)

// global->LDS async copy; size must be a literal (macro keeps it one).
#define GLDS(gptr, lptr, sz)                                                   \
  __builtin_amdgcn_global_load_lds(                                            \
      (const __attribute__((address_space(1))) u32*)(gptr),                    \
      (__attribute__((address_space(3))) u32*)(lptr), sz, 0, 0)

__device__ __forceinline__ unsigned short f2bf(float f) {
  __hip_bfloat16 h = __float2bfloat16(f);
  return __builtin_bit_cast(unsigned short, h);
}

// ---------------- kernel 1: L2-normalize rows, cast to bf16 ----------------
__global__ __launch_bounds__(256) void knorm(const float* __restrict__ emb,
                                             unsigned short* __restrict__ ebf) {
  const int row  = blockIdx.x * 4 + (threadIdx.x >> 6);  // one wave per row
  const int lane = threadIdx.x & 63;
  const float2 v = *reinterpret_cast<const float2*>(emb + (size_t)row * DIM + lane * 2);
  float ss = fmaf(v.x, v.x, v.y * v.y);
#pragma unroll
  for (int off = 32; off > 0; off >>= 1) ss += __shfl_xor(ss, off);
  const float rn = 1.0f / sqrtf(ss);
  const unsigned int packed =
      (unsigned int)f2bf(v.x * rn) | ((unsigned int)f2bf(v.y * rn) << 16);
  *reinterpret_cast<unsigned int*>(ebf + (size_t)row * DIM + lane * 2) = packed;
}

// ---------------- kernel 2: fused sim-GEMM + row stats, 32x32 MFMA ----------------
// 8-wave blocks (512 thr): A-tile shared by 8 waves (half the staging traffic
// and half the barrier instances per j-row vs R8's 4-wave blocks); stage is
// ONE global_load_lds(16B)/thread/tile. Epilogue in packed f32 (float2 ->
// v_pk_fma/add via HIP's fp-contract), threshold via d^2 < T^2 (no fabs).
// Phase rotation (t+bx*5)&15 desynchronizes co-resident blocks' barriers.
// C/D layout (m74/m101): col = lane&31, row = (reg&3)+8*(reg>>2)+4*(lane>>5).
__global__ __launch_bounds__(512) void kmain(const unsigned short* __restrict__ ebf,
                                             const float* __restrict__ props,
                                             float* __restrict__ part) {
  const int tid  = threadIdx.x;
  const int lane = tid & 63;
  const int w    = tid >> 6;           // 0..7
  const int r31  = lane & 31;          // A-row / C-col index
  const int hi   = lane >> 5;          // 0..1
  const int i0   = blockIdx.x * BI;    // block i-range (256 cols)
  const int iw0  = i0 + w * 32;        // wave i-range
  const int jbase = blockIdx.y * CW;

  __shared__ __align__(1024) char sA[2 * TB + CW * 4];
  char* sprops = sA + 2 * TB;

  const int icol = iw0 + r31;          // this lane's output column

  // persistent B-frags: frag kk holds e[icol][kk*16 + hi*8 .. +8)
  v8s bfr[8];
#pragma unroll
  for (int kk = 0; kk < 8; ++kk)
    bfr[kk] = *reinterpret_cast<const v8s*>(ebf + (size_t)icol * DIM + kk * 16 + hi * 8);
  const float pc = props[icol];

  // stage props[jbase .. +512) into LDS: one 4B GLDS per thread
  GLDS(props + jbase + tid, sprops + w * 256, 4);

  // stage one 32-row A-tile: ONE 16B GLDS per thread; LDS linear,
  // source pre-swizzled (LDS chunk s of row r holds global chunk s ^ (r&7))
  auto stageA = [&](char* base, int tile) {
    const int jrow0 = jbase + tile * TILE_J;
    const int row   = w * 4 + (lane >> 4);             // 32 rows over 8 waves
    const int colb  = ((lane & 15) << 4) ^ ((row & 7) << 4);
    GLDS(ebf + (size_t)(jrow0 + row) * DIM + (colb >> 1), base + w * 1024, 16);
  };

  const int phase = (blockIdx.x * 5) & (NT - 1);       // convoy breaker
  stageA(sA, phase);
  __syncthreads();                     // tile(phase) + props ready

  v2f es2 = {0.f, 0.f}, ms2 = {0.f, 0.f}, ct2 = {0.f, 0.f};
  const int rswz = (r31 & 7) << 4;     // read-side XOR swizzle
  const v2f c1v = {C1, C1}, mc1v = {-C1, -C1}, pc2 = {pc, pc};

  for (int t = 0; t < NT; ++t) {
    const int tt = (t + phase) & (NT - 1);
    if (t + 1 < NT) stageA(sA + ((t + 1) & 1) * TB, (tt + 1) & (NT - 1));

    char* base = sA + (t & 1) * TB;
    const int jrow0 = jbase + tt * TILE_J;

    // A-frags: frag kk = e[jrow0 + r31][kk*16 + hi*8 .. +8) via swizzled slot
    v8s af[8];
#pragma unroll
    for (int kk = 0; kk < 8; ++kk)
      af[kk] = *reinterpret_cast<const v8s*>(
          base + r31 * 256 + ((kk * 32 + hi * 16) ^ rswz));

    v16f acc = {0.f, 0.f, 0.f, 0.f, 0.f, 0.f, 0.f, 0.f,
                0.f, 0.f, 0.f, 0.f, 0.f, 0.f, 0.f, 0.f};
#pragma unroll
    for (int kk = 0; kk < 8; ++kk)
      acc = __builtin_amdgcn_mfma_f32_32x32x16_bf16(af[kk], bfr[kk], acc, 0, 0, 0);

    if ((unsigned)(jrow0 - i0) < (unsigned)BI) {   // tile may contain the diagonal
#pragma unroll
      for (int r = 0; r < 8; ++r) {
        const int row0 = ((2 * r) & 3) + 8 * (r >> 1) + 4 * hi;  // rows row0, row0+1
        const v2f pj2  = *reinterpret_cast<const v2f*>(
            sprops + ((size_t)tt * 32 + row0) * 4);              // broadcast read
        const v2f dot2 = {acc[2 * r], acc[2 * r + 1]};
        const v2f arg  = __builtin_elementwise_fma(dot2, c1v, mc1v);
        const float ex0 = __builtin_amdgcn_exp2f(arg.x);
        const float ex1 = __builtin_amdgcn_exp2f(arg.y);
        const int jr0 = jrow0 + row0;
        const bool neq0 = (jr0 != icol), neq1 = (jr0 + 1 != icol);
        const v2f exv = {neq0 ? ex0 : 0.f, neq1 ? ex1 : 0.f};
        es2 += exv;
        const v2f d = pc2 - pj2, dsq = d * d;
        const v2f msk = {(neq0 && dsq.x < T2) ? 1.f : 0.f,
                         (neq1 && dsq.y < T2) ? 1.f : 0.f};
        ct2 += msk;
        ms2 = __builtin_elementwise_fma(msk, dot2, ms2);
      }
    } else {
#pragma unroll
      for (int r = 0; r < 8; ++r) {
        const int row0 = ((2 * r) & 3) + 8 * (r >> 1) + 4 * hi;
        const v2f pj2  = *reinterpret_cast<const v2f*>(
            sprops + ((size_t)tt * 32 + row0) * 4);
        const v2f dot2 = {acc[2 * r], acc[2 * r + 1]};
        const v2f arg  = __builtin_elementwise_fma(dot2, c1v, mc1v);
        const v2f exv  = {__builtin_amdgcn_exp2f(arg.x), __builtin_amdgcn_exp2f(arg.y)};
        es2 += exv;
        const v2f d = pc2 - pj2, dsq = d * d;
        const v2f msk = {(dsq.x < T2) ? 1.f : 0.f, (dsq.y < T2) ? 1.f : 0.f};
        ct2 += msk;
        ms2 = __builtin_elementwise_fma(msk, dot2, ms2);
      }
    }
    __syncthreads();   // all reads of cur done; next tile staged
  }

  // combine pair-halves, then sum the two hi-halves (lanes l and l+32 hold
  // complementary j-row subsets for the same icol)
  float es = es2.x + es2.y, ms = ms2.x + ms2.y, ct = ct2.x + ct2.y;
  es += __shfl_xor(es, 32);
  ms += __shfl_xor(ms, 32);
  ct += __shfl_xor(ct, 32);

  if (hi == 0) {
    float* p0 = part + (size_t)blockIdx.y * 3 * N_ROWS;  // slot = j-split; i disjoint per bx
    p0[icol]              = es;
    p0[N_ROWS + icol]     = ms;
    p0[2 * N_ROWS + icol] = ct;
  }
}

// ---------------- kernel 3: per-row finalize + per-block partial sums ----------------
// 128 blocks x 64 threads (was 32x256): 4x more blocks to spread the
// latency-bound strided slot reads across more CUs.
__global__ __launch_bounds__(64) void kreduce(const float* __restrict__ part,
                                              float* __restrict__ bs,
                                              float* __restrict__ bc) {
  const int row = blockIdx.x * 64 + threadIdx.x;
  float es = 0.f, ms = 0.f, ct = 0.f;
#pragma unroll
  for (int sp = 0; sp < NSLOT; ++sp) {
    const float* p0 = part + (size_t)sp * 3 * N_ROWS;
    es += p0[row];
    ms += p0[N_ROWS + row];
    ct += p0[2 * N_ROWS + row];
  }
  const float lse = 10.0f + logf(es);                       // logsumexp, M=10
  const float per = (ct * lse - 10.0f * ms) / fmaxf(ct, 1.0f);
  float val = (ct > 0.f) ? per : 0.f;
  float vld = (ct > 0.f) ? 1.f : 0.f;
#pragma unroll
  for (int off = 32; off > 0; off >>= 1) {
    val += __shfl_xor(val, off);
    vld += __shfl_xor(vld, off);
  }
  if (threadIdx.x == 0) {
    bs[blockIdx.x] = val;
    bc[blockIdx.x] = vld;
  }
}

// ---------------- kernel 4: final scalar ----------------
__global__ __launch_bounds__(64) void kfin(const float* __restrict__ bs,
                                           const float* __restrict__ bc,
                                           float* __restrict__ out) {
  const int l = threadIdx.x;
  float s = bs[l] + bs[l + 64];
  float c = bc[l] + bc[l + 64];
#pragma unroll
  for (int off = 32; off > 0; off >>= 1) {
    s += __shfl_xor(s, off);
    c += __shfl_xor(c, off);
  }
  if (l == 0) out[0] = (c > 0.f) ? (s / c) : 0.f;
}

extern "C" void kernel_launch(void* const* d_in, const int* in_sizes, int n_in,
                              void* d_out, int out_size, void* d_ws, size_t ws_size,
                              hipStream_t stream) {
  const float* emb   = (const float*)d_in[0];
  const float* props = (const float*)d_in[1];
  float* out = (float*)d_out;

  // ws layout: [0, 2MB) bf16 normalized embeddings; then NSLOT*3*N f32 partials;
  // then 128+128 f32 block partials
  unsigned short* ebf = (unsigned short*)d_ws;
  const size_t EBF_BYTES  = (size_t)N_ROWS * DIM * 2;
  const size_t PART_BYTES = (size_t)NSLOT * 3 * N_ROWS * 4;
  float* part = (float*)((char*)d_ws + EBF_BYTES);
  float* bs   = (float*)((char*)d_ws + EBF_BYTES + PART_BYTES);
  float* bc   = bs + 128;

  knorm<<<N_ROWS / 4, 256, 0, stream>>>(emb, ebf);
  kmain<<<dim3(N_ROWS / BI, NS), 512, 0, stream>>>(ebf, props, part);
  kreduce<<<N_ROWS / 64, 64, 0, stream>>>(part, bs, bc);
  kfin<<<1, 64, 0, stream>>>(bs, bc, out);
}